// Round 3
// baseline (238.582 us; speedup 1.0000x reference)
//
#include <hip/hip_runtime.h>

#define R   256
#define S   128
#define CM  256
#define CH  32
#define CZ  128

typedef __attribute__((ext_vector_type(8))) short short8;
typedef __attribute__((ext_vector_type(4))) float f32x4;
typedef unsigned short ushort_t;

__device__ inline ushort_t f2bf(float f) {
    union { float f; unsigned u; } v; v.f = f;
    unsigned u = v.u;
    unsigned r = u + 0x7FFF + ((u >> 16) & 1);
    return (ushort_t)(r >> 16);
}

// ---------------------------------------------------------------------------
// K0: WcatT only (must precede k_lnproj, which consumes it).
//   64 blocks: WcatT[ch][k] = bf16(ch<32 ? w1[k][ch] : w2[k][ch-32])
// ---------------------------------------------------------------------------
__global__ __launch_bounds__(256) void k_prepW(
    const float* __restrict__ w1, const float* __restrict__ w2,
    ushort_t* __restrict__ WcatT) {
    int ch = blockIdx.x, k = threadIdx.x;
    const float* w = (ch < CH) ? w1 : w2;
    WcatT[(size_t)ch * CM + k] = f2bf(w[(size_t)k * CH + (ch & 31)]);
}

// ---------------------------------------------------------------------------
// K1 (merged): LN+proj (blocks [0,512)), scale (blocks [512,1536)),
// WTp transpose (blocks [1536,1664)). scale/WTp feed only k_fuse, so they
// ride in this launch for free overlap with the LN work.
// ---------------------------------------------------------------------------
__global__ __launch_bounds__(256) void k_lnproj(
    const float* __restrict__ m, const float* __restrict__ mask,
    const float* __restrict__ g, const float* __restrict__ beta,
    const float* __restrict__ b1, const float* __restrict__ b2,
    const ushort_t* __restrict__ WcatT, const float* __restrict__ w_out,
    ushort_t* __restrict__ Abig, ushort_t* __restrict__ BbigT,
    float* __restrict__ scale, ushort_t* __restrict__ WTp) {
    __shared__ ushort_t mnL[64 * CM];      // 32 KB (aliased by scale branch)
    int t = threadIdx.x;
    int b = blockIdx.x;

    if (b >= 1536) {                       // ---- WTp transpose ----
        int z = b - 1536;
        #pragma unroll
        for (int q = 0; q < 4; ++q) {
            int k2 = q * 256 + t;
            int e = k2 >> 5, c = k2 & 31;
            WTp[(size_t)z * 1024 + k2] = f2bf(w_out[(size_t)(c * 32 + e) * CZ + z]);
        }
        return;
    }
    if (b >= 512) {                        // ---- scale ----
        float* red = (float*)mnL;          // [4][64]
        int bb = b - 512;
        int i = bb >> 2, jq = bb & 3;
        int jl = t & 63, wv = t >> 6;
        int j = jq * 64 + jl;
        const float* mi = mask + (size_t)(wv * 32) * R + i;
        const float* mj = mask + (size_t)(wv * 32) * R + j;
        float acc = 0.f;
        #pragma unroll
        for (int s = 0; s < 32; ++s) acc += mi[s * R] * mj[s * R];
        red[wv * 64 + jl] = acc;
        __syncthreads();
        if (t < 64) {
            float v = red[t] + red[64 + t] + red[128 + t] + red[192 + t];
            scale[(size_t)i * R + jq * 64 + t] = 1.0f / (1e-3f + v);
        }
        return;
    }

    // ---- LN + projections ----
    int sg = b & 7, rg = b >> 3;
    int s0 = sg * 16, r0 = rg * 4;

    int ml = t >> 2, part = t & 3;
    int r_l = ml >> 4, s_l = ml & 15;
    size_t p = (size_t)(s0 + s_l) * R + (r0 + r_l);
    const float4* row = (const float4*)(m + p * CM + part * 64);
    float4 x[16];
    float sum = 0.f, sq = 0.f;
    #pragma unroll
    for (int i = 0; i < 16; ++i) {
        x[i] = row[i];
        sum += x[i].x + x[i].y + x[i].z + x[i].w;
        sq  += x[i].x * x[i].x + x[i].y * x[i].y
             + x[i].z * x[i].z + x[i].w * x[i].w;
    }
    sum += __shfl_xor(sum, 1); sum += __shfl_xor(sum, 2);
    sq  += __shfl_xor(sq, 1);  sq  += __shfl_xor(sq, 2);
    float mean = sum * (1.0f / CM);
    float var  = sq * (1.0f / CM) - mean * mean;
    float inv  = rsqrtf(var + 1e-5f);
    const float4* g4 = (const float4*)(g + part * 64);
    const float4* be4 = (const float4*)(beta + part * 64);
    #pragma unroll
    for (int c8 = 0; c8 < 8; ++c8) {
        float4 a = x[2 * c8], bq = x[2 * c8 + 1];
        float4 ga = g4[2 * c8], gb = g4[2 * c8 + 1];
        float4 ba = be4[2 * c8], bb = be4[2 * c8 + 1];
        union { ushort_t u[8]; uint4 v; } pk;
        pk.u[0] = f2bf((a.x - mean) * inv * ga.x + ba.x);
        pk.u[1] = f2bf((a.y - mean) * inv * ga.y + ba.y);
        pk.u[2] = f2bf((a.z - mean) * inv * ga.z + ba.z);
        pk.u[3] = f2bf((a.w - mean) * inv * ga.w + ba.w);
        pk.u[4] = f2bf((bq.x - mean) * inv * gb.x + bb.x);
        pk.u[5] = f2bf((bq.y - mean) * inv * gb.y + bb.y);
        pk.u[6] = f2bf((bq.z - mean) * inv * gb.z + bb.z);
        pk.u[7] = f2bf((bq.w - mean) * inv * gb.w + bb.w);
        int ck = part * 8 + c8;
        int phys = ck ^ (ml & 15);
        *(uint4*)&mnL[ml * CM + phys * 8] = pk.v;
    }

    // W fragments: register-resident from L2.
    int w = t >> 6, lane = t & 63, quad = lane >> 4, l15 = lane & 15;
    int ch = w * 16 + l15;
    short8 bfrs[8];
    #pragma unroll
    for (int ks = 0; ks < 8; ++ks)
        bfrs[ks] = *(const short8*)&WcatT[(size_t)ch * CM + (ks * 4 + quad) * 8];
    __syncthreads();

    f32x4 acc[4];
    #pragma unroll
    for (int a = 0; a < 4; a++) acc[a] = (f32x4)(0.f);
    #pragma unroll
    for (int ks = 0; ks < 8; ++ks) {
        int cb = ks * 4 + quad;
        #pragma unroll
        for (int mt = 0; mt < 4; ++mt) {
            int mm = mt * 16 + l15;
            short8 afr = *(const short8*)&mnL[mm * CM + ((cb ^ l15) << 3)];
            acc[mt] = __builtin_amdgcn_mfma_f32_16x16x32_bf16(afr, bfrs[ks], acc[mt], 0, 0, 0);
        }
    }

    int c = ch & 31;
    float bias = (ch < CH) ? b1[c] : b2[c];
    ushort_t* dst = (ch < CH) ? Abig : BbigT;
    #pragma unroll
    for (int mt = 0; mt < 4; ++mt) {
        int r = r0 + mt;
        union { ushort_t u[4]; uint2 v; } pk;
        #pragma unroll
        for (int reg = 0; reg < 4; ++reg) {
            int s = s0 + quad * 4 + reg;
            float mv = mask[(size_t)s * R + r];
            pk.u[reg] = f2bf((acc[mt][reg] + bias) * mv);
        }
        *(uint2*)&dst[((size_t)r * CH + c) * S + s0 + quad * 4] = pk.v;
    }
}

// ---------------------------------------------------------------------------
// K2: fused outer-product + projection, LDS-traffic-minimized.
//  - shB removed: stage-1 B-frags load direct from BbigT (L2-resident,
//    coalesced 16 rows x 64B, same pattern as af). One barrier per iter.
//  - oc double-buffered (2 x 16 KB) -> stage-2 reads iter ec's buffer while
//    next iter writes the other; single __syncthreads per iter.
//  - stage-2 split: wave = (pair-half ph = w>>2) x (z-quarter zq = w&3).
//    A-frags reused over 2 z-tiles -> 8 ds_read_b128 per wave-iter (was 16).
//  - oc swizzle widened to 4 bits (cc ^ (pp&15)): read instrs now span all
//    16 slots / 32 banks (was 8 slots -> ~8-way conflicts).
// ---------------------------------------------------------------------------
__global__ __launch_bounds__(512) void k_fuse(
    const ushort_t* __restrict__ Abig, const ushort_t* __restrict__ BbigT,
    const ushort_t* __restrict__ WTp, const float* __restrict__ b_out,
    const float* __restrict__ scale, float* __restrict__ out) {
    __shared__ ushort_t oc[2][64 * 128];     // 2 x 16 KB, double-buffered
    int t = threadIdx.x;
    int w = t >> 6, lane = t & 63, quad = lane >> 4, l15 = lane & 15;
    int ib = blockIdx.x >> 5, jb = blockIdx.x & 31;
    int i_g = ib * 8 + w;
    int jj = l15 & 7, elb = l15 >> 3;

    // A-frags for this wave's i-strip (register-resident, 8 iters of reuse)
    short8 af[2][4];
    #pragma unroll
    for (int mt = 0; mt < 2; ++mt)
        #pragma unroll
        for (int ks = 0; ks < 4; ++ks)
            af[mt][ks] = *(const short8*)
                &Abig[((size_t)i_g * 32 + mt * 16 + l15) * S + ks * 32 + quad * 8];

    // B direct-load base: logical B row (n-dim) = j*32 + e; lane l15 covers
    // (jj, elb); per iter ec and half nt: row = jj*32 + ec*4 + nt*2 + elb.
    const ushort_t* gB = BbigT + ((size_t)jb * 256 + jj * 32 + elb) * S + quad * 8;

    // W base: wave's z-quarter zq = w&3; z-row = zq*32 + zt*16 + l15.
    const ushort_t* Wp = WTp + ((size_t)((w & 3) * 32) + l15) * 1024 + quad * 8;

    int ph = w >> 2;                         // pair-half for stage-2
    int pwr = w * 8 + jj;                    // oc pair-row this lane writes

    f32x4 acc2[2][2];                        // [mtile][zt]
    #pragma unroll
    for (int a = 0; a < 2; ++a)
        #pragma unroll
        for (int zt = 0; zt < 2; ++zt) acc2[a][zt] = (f32x4)(0.f);

    // prologue: B for ec=0
    short8 bcur[2][4];
    #pragma unroll
    for (int nt = 0; nt < 2; ++nt)
        #pragma unroll
        for (int ks = 0; ks < 4; ++ks)
            bcur[nt][ks] = *(const short8*)&gB[(size_t)(nt * 2) * S + ks * 32];

    #pragma unroll
    for (int ec = 0; ec < 8; ++ec) {
        // ---- stage-1: OC chunk (e = ec*4 .. ec*4+3) ----
        f32x4 acc1[2][2];
        #pragma unroll
        for (int a = 0; a < 2; a++)
            #pragma unroll
            for (int bq = 0; bq < 2; bq++) acc1[a][bq] = (f32x4)(0.f);
        #pragma unroll
        for (int ks = 0; ks < 4; ++ks) {
            #pragma unroll
            for (int mt = 0; mt < 2; ++mt) {
                acc1[mt][0] = __builtin_amdgcn_mfma_f32_16x16x32_bf16(
                    af[mt][ks], bcur[0][ks], acc1[mt][0], 0, 0, 0);
                acc1[mt][1] = __builtin_amdgcn_mfma_f32_16x16x32_bf16(
                    af[mt][ks], bcur[1][ks], acc1[mt][1], 0, 0, 0);
            }
        }
        // pack to oc[ec&1]: lane's 4 regs = 4 consecutive c at (pwr, e)
        #pragma unroll
        for (int mt = 0; mt < 2; ++mt) {
            int c00 = mt * 16 + quad * 4;
            #pragma unroll
            for (int nt = 0; nt < 2; ++nt) {
                int el = nt * 2 + elb;
                int k2l = el * 32 + c00;
                int cc = k2l >> 3;
                union { ushort_t u[4]; uint2 v; } pk;
                #pragma unroll
                for (int reg = 0; reg < 4; ++reg)
                    pk.u[reg] = f2bf(acc1[mt][nt][reg]);
                *(uint2*)((char*)oc[ec & 1] + pwr * 256
                          + ((cc ^ (pwr & 15)) << 4) + ((k2l & 7) << 1)) = pk.v;
            }
        }
        __syncthreads();   // publish oc[ec&1] (only barrier this iter)

        // prefetch B for ec+1 (consumed after stage-2 -> latency hidden)
        if (ec < 7) {
            #pragma unroll
            for (int nt = 0; nt < 2; ++nt)
                #pragma unroll
                for (int ks = 0; ks < 4; ++ks)
                    bcur[nt][ks] = *(const short8*)
                        &gB[(size_t)((ec + 1) * 4 + nt * 2) * S + ks * 32];
        }

        // ---- stage-2: out += OC[ph half] x W[zq quarter] ----
        #pragma unroll
        for (int ksl = 0; ksl < 4; ++ksl) {
            short8 wf0 = *(const short8*)&Wp[ec * 128 + ksl * 32];
            short8 wf1 = *(const short8*)&Wp[16 * 1024 + ec * 128 + ksl * 32];
            #pragma unroll
            for (int mtile = 0; mtile < 2; ++mtile) {
                int pp = ph * 32 + mtile * 16 + l15;
                int cc2 = ksl * 4 + quad;
                short8 of = *(const short8*)
                    ((const char*)oc[ec & 1] + pp * 256 + ((cc2 ^ (pp & 15)) << 4));
                acc2[mtile][0] = __builtin_amdgcn_mfma_f32_16x16x32_bf16(
                    of, wf0, acc2[mtile][0], 0, 0, 0);
                acc2[mtile][1] = __builtin_amdgcn_mfma_f32_16x16x32_bf16(
                    of, wf1, acc2[mtile][1], 0, 0, 0);
            }
        }
    }

    // ---- epilogue: bias + 1/(eps+norm) scale ----
    float bz0 = b_out[(w & 3) * 32 + l15];
    float bz1 = b_out[(w & 3) * 32 + 16 + l15];
    #pragma unroll
    for (int mtile = 0; mtile < 2; ++mtile) {
        #pragma unroll
        for (int reg = 0; reg < 4; ++reg) {
            int pq = ph * 32 + mtile * 16 + quad * 4 + reg;
            int pg = (ib * 8 + (pq >> 3)) * R + jb * 8 + (pq & 7);
            float sc = scale[pg];
            out[(size_t)pg * CZ + (w & 3) * 32 + l15]
                = (acc2[mtile][0][reg] + bz0) * sc;
            out[(size_t)pg * CZ + (w & 3) * 32 + 16 + l15]
                = (acc2[mtile][1][reg] + bz1) * sc;
        }
    }
}

// ---------------------------------------------------------------------------
extern "C" void kernel_launch(void* const* d_in, const int* in_sizes, int n_in,
                              void* d_out, int out_size, void* d_ws, size_t ws_size,
                              hipStream_t stream) {
    const float* m    = (const float*)d_in[0];
    const float* mask = (const float*)d_in[1];
    const float* g    = (const float*)d_in[2];
    const float* be   = (const float*)d_in[3];
    const float* w1   = (const float*)d_in[4];
    const float* b1   = (const float*)d_in[5];
    const float* w2   = (const float*)d_in[6];
    const float* b2   = (const float*)d_in[7];
    const float* wo   = (const float*)d_in[8];
    const float* bo   = (const float*)d_in[9];
    float* out = (float*)d_out;

    char* ws = (char*)d_ws;
    ushort_t* Abig  = (ushort_t*)ws;                        // 2 MB
    ushort_t* BbigT = Abig + (size_t)R * CH * S;            // 2 MB
    ushort_t* WTp   = BbigT + (size_t)R * CH * S;           // 256 KB
    ushort_t* WcatT = WTp + (size_t)CZ * CH * CH;           // 32 KB
    float*    scale = (float*)(WcatT + (size_t)64 * CM);    // 256 KB

    k_prepW<<<64, 256, 0, stream>>>(w1, w2, WcatT);
    k_lnproj<<<1664, 256, 0, stream>>>(m, mask, g, be, b1, b2, WcatT, wo,
                                       Abig, BbigT, scale, WTp);
    k_fuse<<<1024, 512, 0, stream>>>(Abig, BbigT, WTp, bo, scale, out);
}

// Round 4
// 183.926 us; speedup vs baseline: 1.2972x; 1.2972x over previous
//
#include <hip/hip_runtime.h>

#define R   256
#define S   128
#define CM  256
#define CH  32
#define CZ  128

typedef __attribute__((ext_vector_type(8))) short short8;
typedef __attribute__((ext_vector_type(4))) float f32x4;
typedef unsigned short ushort_t;

__device__ inline ushort_t f2bf(float f) {
    union { float f; unsigned u; } v; v.f = f;
    unsigned u = v.u;
    unsigned r = u + 0x7FFF + ((u >> 16) & 1);
    return (ushort_t)(r >> 16);
}

// ---------------------------------------------------------------------------
// K0: WcatT only (must precede k_lnproj, which consumes it).
// ---------------------------------------------------------------------------
__global__ __launch_bounds__(256) void k_prepW(
    const float* __restrict__ w1, const float* __restrict__ w2,
    ushort_t* __restrict__ WcatT) {
    int ch = blockIdx.x, k = threadIdx.x;
    const float* w = (ch < CH) ? w1 : w2;
    WcatT[(size_t)ch * CM + k] = f2bf(w[(size_t)k * CH + (ch & 31)]);
}

// ---------------------------------------------------------------------------
// K1 (merged): LN+proj (blocks [0,512)), scale (blocks [512,1536)),
// WTp transpose (blocks [1536,1664)).
// ---------------------------------------------------------------------------
__global__ __launch_bounds__(256) void k_lnproj(
    const float* __restrict__ m, const float* __restrict__ mask,
    const float* __restrict__ g, const float* __restrict__ beta,
    const float* __restrict__ b1, const float* __restrict__ b2,
    const ushort_t* __restrict__ WcatT, const float* __restrict__ w_out,
    ushort_t* __restrict__ Abig, ushort_t* __restrict__ BbigT,
    float* __restrict__ scale, ushort_t* __restrict__ WTp) {
    __shared__ ushort_t mnL[64 * CM];      // 32 KB (aliased by scale branch)
    int t = threadIdx.x;
    int b = blockIdx.x;

    if (b >= 1536) {                       // ---- WTp transpose ----
        int z = b - 1536;
        #pragma unroll
        for (int q = 0; q < 4; ++q) {
            int k2 = q * 256 + t;
            int e = k2 >> 5, c = k2 & 31;
            WTp[(size_t)z * 1024 + k2] = f2bf(w_out[(size_t)(c * 32 + e) * CZ + z]);
        }
        return;
    }
    if (b >= 512) {                        // ---- scale ----
        float* red = (float*)mnL;          // [4][64]
        int bb = b - 512;
        int i = bb >> 2, jq = bb & 3;
        int jl = t & 63, wv = t >> 6;
        int j = jq * 64 + jl;
        const float* mi = mask + (size_t)(wv * 32) * R + i;
        const float* mj = mask + (size_t)(wv * 32) * R + j;
        float acc = 0.f;
        #pragma unroll
        for (int s = 0; s < 32; ++s) acc += mi[s * R] * mj[s * R];
        red[wv * 64 + jl] = acc;
        __syncthreads();
        if (t < 64) {
            float v = red[t] + red[64 + t] + red[128 + t] + red[192 + t];
            scale[(size_t)i * R + jq * 64 + t] = 1.0f / (1e-3f + v);
        }
        return;
    }

    // ---- LN + projections ----
    int sg = b & 7, rg = b >> 3;
    int s0 = sg * 16, r0 = rg * 4;

    int ml = t >> 2, part = t & 3;
    int r_l = ml >> 4, s_l = ml & 15;
    size_t p = (size_t)(s0 + s_l) * R + (r0 + r_l);
    const float4* row = (const float4*)(m + p * CM + part * 64);
    float4 x[16];
    float sum = 0.f, sq = 0.f;
    #pragma unroll
    for (int i = 0; i < 16; ++i) {
        x[i] = row[i];
        sum += x[i].x + x[i].y + x[i].z + x[i].w;
        sq  += x[i].x * x[i].x + x[i].y * x[i].y
             + x[i].z * x[i].z + x[i].w * x[i].w;
    }
    sum += __shfl_xor(sum, 1); sum += __shfl_xor(sum, 2);
    sq  += __shfl_xor(sq, 1);  sq  += __shfl_xor(sq, 2);
    float mean = sum * (1.0f / CM);
    float var  = sq * (1.0f / CM) - mean * mean;
    float inv  = rsqrtf(var + 1e-5f);
    const float4* g4 = (const float4*)(g + part * 64);
    const float4* be4 = (const float4*)(beta + part * 64);
    #pragma unroll
    for (int c8 = 0; c8 < 8; ++c8) {
        float4 a = x[2 * c8], bq = x[2 * c8 + 1];
        float4 ga = g4[2 * c8], gb = g4[2 * c8 + 1];
        float4 ba = be4[2 * c8], bb = be4[2 * c8 + 1];
        union { ushort_t u[8]; uint4 v; } pk;
        pk.u[0] = f2bf((a.x - mean) * inv * ga.x + ba.x);
        pk.u[1] = f2bf((a.y - mean) * inv * ga.y + ba.y);
        pk.u[2] = f2bf((a.z - mean) * inv * ga.z + ba.z);
        pk.u[3] = f2bf((a.w - mean) * inv * ga.w + ba.w);
        pk.u[4] = f2bf((bq.x - mean) * inv * gb.x + bb.x);
        pk.u[5] = f2bf((bq.y - mean) * inv * gb.y + bb.y);
        pk.u[6] = f2bf((bq.z - mean) * inv * gb.z + bb.z);
        pk.u[7] = f2bf((bq.w - mean) * inv * gb.w + bb.w);
        int ck = part * 8 + c8;
        int phys = ck ^ (ml & 15);
        *(uint4*)&mnL[ml * CM + phys * 8] = pk.v;
    }

    // W fragments: register-resident from L2.
    int w = t >> 6, lane = t & 63, quad = lane >> 4, l15 = lane & 15;
    int ch = w * 16 + l15;
    short8 bfrs[8];
    #pragma unroll
    for (int ks = 0; ks < 8; ++ks)
        bfrs[ks] = *(const short8*)&WcatT[(size_t)ch * CM + (ks * 4 + quad) * 8];
    __syncthreads();

    f32x4 acc[4];
    #pragma unroll
    for (int a = 0; a < 4; a++) acc[a] = (f32x4)(0.f);
    #pragma unroll
    for (int ks = 0; ks < 8; ++ks) {
        int cb = ks * 4 + quad;
        #pragma unroll
        for (int mt = 0; mt < 4; ++mt) {
            int mm = mt * 16 + l15;
            short8 afr = *(const short8*)&mnL[mm * CM + ((cb ^ l15) << 3)];
            acc[mt] = __builtin_amdgcn_mfma_f32_16x16x32_bf16(afr, bfrs[ks], acc[mt], 0, 0, 0);
        }
    }

    int c = ch & 31;
    float bias = (ch < CH) ? b1[c] : b2[c];
    ushort_t* dst = (ch < CH) ? Abig : BbigT;
    #pragma unroll
    for (int mt = 0; mt < 4; ++mt) {
        int r = r0 + mt;
        union { ushort_t u[4]; uint2 v; } pk;
        #pragma unroll
        for (int reg = 0; reg < 4; ++reg) {
            int s = s0 + quad * 4 + reg;
            float mv = mask[(size_t)s * R + r];
            pk.u[reg] = f2bf((acc[mt][reg] + bias) * mv);
        }
        *(uint2*)&dst[((size_t)r * CH + c) * S + s0 + quad * 4] = pk.v;
    }
}

// ---------------------------------------------------------------------------
// K2: fused outer-product + projection. Hybrid of R2 (shB LDS staging for B
// — coalesced 1x traffic, ds_read operands) and R3 (4-bit oc swizzle,
// double-buffered oc, ph x zq stage-2 split). Single barrier per iter:
//   ds_write shB[next] | stage-1(shB[cur]) | pack oc[cur] | B prefetch ec+2
//   | W(ec) -> regs | barrier | stage-2(oc[cur] x Wregs)
// All buffer read/write pairs are separated by exactly one barrier.
// __launch_bounds__(512,4): VGPR<=128 -> 2 blocks/CU so blocks cover each
// other's barrier waits.
// ---------------------------------------------------------------------------
__global__ __launch_bounds__(512, 4) void k_fuse(
    const ushort_t* __restrict__ Abig, const ushort_t* __restrict__ BbigT,
    const ushort_t* __restrict__ WTp, const float* __restrict__ b_out,
    const float* __restrict__ scale, float* __restrict__ out) {
    __shared__ ushort_t oc[2][64 * 128];     // 2 x 16 KB
    __shared__ ushort_t shB[2][32 * 128];    // 2 x 8 KB, [esub*8+j][s] swizzled
    int t = threadIdx.x;
    int w = t >> 6, lane = t & 63, quad = lane >> 4, l15 = lane & 15;
    int ib = blockIdx.x >> 5, jb = blockIdx.x & 31;
    int i_g = ib * 8 + w;
    int jj = l15 & 7, elb = l15 >> 3;

    // A-frags for this wave's i-strip (register-resident, coalesced loads)
    short8 af[2][4];
    #pragma unroll
    for (int mt = 0; mt < 2; ++mt)
        #pragma unroll
        for (int ks = 0; ks < 4; ++ks)
            af[mt][ks] = *(const short8*)
                &Abig[((size_t)i_g * 32 + mt * 16 + l15) * S + ks * 32 + quad * 8];

    // B staging: thread t owns LDS row r2 = t>>4 (0..31), 16B chunk ck = t&15
    // global row = jb*256 + (r2&7)*32 + ec*4 + (r2>>3)
    int r2 = t >> 4, ck = t & 15;
    const ushort_t* gB = BbigT
        + ((size_t)jb * 256 + (r2 & 7) * 32 + (r2 >> 3)) * S + ck * 8;
    ushort_t* bdst[2];
    bdst[0] = &shB[0][r2 * 128 + ((ck ^ (r2 & 15)) << 3)];
    bdst[1] = &shB[1][r2 * 128 + ((ck ^ (r2 & 15)) << 3)];

    // W base: wave's z-quarter zq = w&3; z-row = zq*32 + zt*16 + l15.
    const ushort_t* Wp = WTp + ((size_t)((w & 3) * 32) + l15) * 1024 + quad * 8;

    int ph = w >> 2;                         // pair-half for stage-2
    int pwr = w * 8 + jj;                    // oc pair-row this lane writes

    f32x4 acc2[2][2];                        // [mtile][zt]
    #pragma unroll
    for (int a = 0; a < 2; ++a)
        #pragma unroll
        for (int zt = 0; zt < 2; ++zt) acc2[a][zt] = (f32x4)(0.f);

    // prologue: stage slice 0, then prefetch slice 1
    uint4 breg = *(const uint4*)&gB[0];
    *(uint4*)bdst[0] = breg;
    __syncthreads();
    breg = *(const uint4*)&gB[512];

    #pragma unroll
    for (int ec = 0; ec < 8; ++ec) {
        int buf = ec & 1;
        // publish next B slice into the other buffer (read next iter)
        if (ec < 7) *(uint4*)bdst[(ec + 1) & 1] = breg;

        // ---- stage-1: OC chunk (e = ec*4 .. ec*4+3) ----
        f32x4 acc1[2][2];
        #pragma unroll
        for (int a = 0; a < 2; a++)
            #pragma unroll
            for (int bq = 0; bq < 2; bq++) acc1[a][bq] = (f32x4)(0.f);
        #pragma unroll
        for (int ks = 0; ks < 4; ++ks) {
            int chq = ks * 4 + quad;
            int r20 = elb * 8 + jj;          // nt=0: e = ec*4 + elb
            int r21 = r20 + 16;              // nt=1: e = ec*4 + 2 + elb
            short8 bf0 = *(const short8*)
                &shB[buf][r20 * 128 + ((chq ^ (r20 & 15)) << 3)];
            short8 bf1 = *(const short8*)
                &shB[buf][r21 * 128 + ((chq ^ (r21 & 15)) << 3)];
            #pragma unroll
            for (int mt = 0; mt < 2; ++mt) {
                acc1[mt][0] = __builtin_amdgcn_mfma_f32_16x16x32_bf16(
                    af[mt][ks], bf0, acc1[mt][0], 0, 0, 0);
                acc1[mt][1] = __builtin_amdgcn_mfma_f32_16x16x32_bf16(
                    af[mt][ks], bf1, acc1[mt][1], 0, 0, 0);
            }
        }
        // pack to oc[buf]: lane's 4 regs = 4 consecutive c at (pwr, e)
        #pragma unroll
        for (int mt = 0; mt < 2; ++mt) {
            int c00 = mt * 16 + quad * 4;
            #pragma unroll
            for (int nt = 0; nt < 2; ++nt) {
                int el = nt * 2 + elb;
                int k2l = el * 32 + c00;
                int cc = k2l >> 3;
                union { ushort_t u[4]; uint2 v; } pk;
                #pragma unroll
                for (int reg = 0; reg < 4; ++reg)
                    pk.u[reg] = f2bf(acc1[mt][nt][reg]);
                *(uint2*)((char*)oc[buf] + pwr * 256
                          + ((cc ^ (pwr & 15)) << 4) + ((k2l & 7) << 1)) = pk.v;
            }
        }

        // prefetch B slice ec+2 (consumed in iter ec+1's publish)
        if (ec < 6) breg = *(const uint4*)&gB[(ec + 2) * 512];

        // W fragments for this ec -> registers (issued before barrier,
        // consumed after: latency hidden under barrier wait + oc writes)
        short8 wreg[2][4];
        #pragma unroll
        for (int zt = 0; zt < 2; ++zt)
            #pragma unroll
            for (int ksl = 0; ksl < 4; ++ksl)
                wreg[zt][ksl] = *(const short8*)
                    &Wp[(size_t)zt * 16 * 1024 + ec * 128 + ksl * 32];

        __syncthreads();   // publishes oc[buf] + shB[(ec+1)&1]

        // ---- stage-2: out += OC[ph half] x W[zq quarter] ----
        #pragma unroll
        for (int ksl = 0; ksl < 4; ++ksl) {
            #pragma unroll
            for (int mtile = 0; mtile < 2; ++mtile) {
                int pp = ph * 32 + mtile * 16 + l15;
                int cc2 = ksl * 4 + quad;
                short8 of = *(const short8*)
                    ((const char*)oc[buf] + pp * 256 + ((cc2 ^ (pp & 15)) << 4));
                acc2[mtile][0] = __builtin_amdgcn_mfma_f32_16x16x32_bf16(
                    of, wreg[0][ksl], acc2[mtile][0], 0, 0, 0);
                acc2[mtile][1] = __builtin_amdgcn_mfma_f32_16x16x32_bf16(
                    of, wreg[1][ksl], acc2[mtile][1], 0, 0, 0);
            }
        }
    }

    // ---- epilogue: bias + 1/(eps+norm) scale ----
    float bz0 = b_out[(w & 3) * 32 + l15];
    float bz1 = b_out[(w & 3) * 32 + 16 + l15];
    #pragma unroll
    for (int mtile = 0; mtile < 2; ++mtile) {
        #pragma unroll
        for (int reg = 0; reg < 4; ++reg) {
            int pq = ph * 32 + mtile * 16 + quad * 4 + reg;
            int pg = (ib * 8 + (pq >> 3)) * R + jb * 8 + (pq & 7);
            float sc = scale[pg];
            out[(size_t)pg * CZ + (w & 3) * 32 + l15]
                = (acc2[mtile][0][reg] + bz0) * sc;
            out[(size_t)pg * CZ + (w & 3) * 32 + 16 + l15]
                = (acc2[mtile][1][reg] + bz1) * sc;
        }
    }
}

// ---------------------------------------------------------------------------
extern "C" void kernel_launch(void* const* d_in, const int* in_sizes, int n_in,
                              void* d_out, int out_size, void* d_ws, size_t ws_size,
                              hipStream_t stream) {
    const float* m    = (const float*)d_in[0];
    const float* mask = (const float*)d_in[1];
    const float* g    = (const float*)d_in[2];
    const float* be   = (const float*)d_in[3];
    const float* w1   = (const float*)d_in[4];
    const float* b1   = (const float*)d_in[5];
    const float* w2   = (const float*)d_in[6];
    const float* b2   = (const float*)d_in[7];
    const float* wo   = (const float*)d_in[8];
    const float* bo   = (const float*)d_in[9];
    float* out = (float*)d_out;

    char* ws = (char*)d_ws;
    ushort_t* Abig  = (ushort_t*)ws;                        // 2 MB
    ushort_t* BbigT = Abig + (size_t)R * CH * S;            // 2 MB
    ushort_t* WTp   = BbigT + (size_t)R * CH * S;           // 256 KB
    ushort_t* WcatT = WTp + (size_t)CZ * CH * CH;           // 32 KB
    float*    scale = (float*)(WcatT + (size_t)64 * CM);    // 256 KB

    k_prepW<<<64, 256, 0, stream>>>(w1, w2, WcatT);
    k_lnproj<<<1664, 256, 0, stream>>>(m, mask, g, be, b1, b2, WcatT, wo,
                                       Abig, BbigT, scale, WTp);
    k_fuse<<<1024, 512, 0, stream>>>(Abig, BbigT, WTp, bo, scale, out);
}

// Round 5
// 156.268 us; speedup vs baseline: 1.5267x; 1.1770x over previous
//
#include <hip/hip_runtime.h>

#define R   256
#define S   128
#define CM  256
#define CH  32
#define CZ  128

typedef __attribute__((ext_vector_type(8))) short short8;
typedef __attribute__((ext_vector_type(4))) float f32x4;
typedef unsigned short ushort_t;

__device__ inline ushort_t f2bf(float f) {
    union { float f; unsigned u; } v; v.f = f;
    unsigned u = v.u;
    unsigned r = u + 0x7FFF + ((u >> 16) & 1);
    return (ushort_t)(r >> 16);
}

// ---------------------------------------------------------------------------
// K1 (merged): LN+proj (blocks [0,512)), scale (blocks [512,1536)),
// WTp transpose (blocks [1536,1664)). k_prepW eliminated: LN waves gather
// their W fragments directly from w1/w2 (L2-resident, overlapped with the
// mnL pack + barrier window).
// ---------------------------------------------------------------------------
__global__ __launch_bounds__(256) void k_lnproj(
    const float* __restrict__ m, const float* __restrict__ mask,
    const float* __restrict__ g, const float* __restrict__ beta,
    const float* __restrict__ b1, const float* __restrict__ b2,
    const float* __restrict__ w1, const float* __restrict__ w2,
    const float* __restrict__ w_out,
    ushort_t* __restrict__ Abig, ushort_t* __restrict__ BbigT,
    float* __restrict__ scale, ushort_t* __restrict__ WTp) {
    __shared__ ushort_t mnL[64 * CM];      // 32 KB (aliased by scale branch)
    int t = threadIdx.x;
    int b = blockIdx.x;

    if (b >= 1536) {                       // ---- WTp transpose ----
        int z = b - 1536;
        #pragma unroll
        for (int q = 0; q < 4; ++q) {
            int k2 = q * 256 + t;
            int e = k2 >> 5, c = k2 & 31;
            WTp[(size_t)z * 1024 + k2] = f2bf(w_out[(size_t)(c * 32 + e) * CZ + z]);
        }
        return;
    }
    if (b >= 512) {                        // ---- scale ----
        float* red = (float*)mnL;          // [4][64]
        int bb = b - 512;
        int i = bb >> 2, jq = bb & 3;
        int jl = t & 63, wv = t >> 6;
        int j = jq * 64 + jl;
        const float* mi = mask + (size_t)(wv * 32) * R + i;
        const float* mj = mask + (size_t)(wv * 32) * R + j;
        float acc = 0.f;
        #pragma unroll
        for (int s = 0; s < 32; ++s) acc += mi[s * R] * mj[s * R];
        red[wv * 64 + jl] = acc;
        __syncthreads();
        if (t < 64) {
            float v = red[t] + red[64 + t] + red[128 + t] + red[192 + t];
            scale[(size_t)i * R + jq * 64 + t] = 1.0f / (1e-3f + v);
        }
        return;
    }

    // ---- LN + projections ----
    int sg = b & 7, rg = b >> 3;
    int s0 = sg * 16, r0 = rg * 4;

    int ml = t >> 2, part = t & 3;
    int r_l = ml >> 4, s_l = ml & 15;
    size_t p = (size_t)(s0 + s_l) * R + (r0 + r_l);
    const float4* row = (const float4*)(m + p * CM + part * 64);
    float4 x[16];
    float sum = 0.f, sq = 0.f;
    #pragma unroll
    for (int i = 0; i < 16; ++i) {
        x[i] = row[i];
        sum += x[i].x + x[i].y + x[i].z + x[i].w;
        sq  += x[i].x * x[i].x + x[i].y * x[i].y
             + x[i].z * x[i].z + x[i].w * x[i].w;
    }
    sum += __shfl_xor(sum, 1); sum += __shfl_xor(sum, 2);
    sq  += __shfl_xor(sq, 1);  sq  += __shfl_xor(sq, 2);
    float mean = sum * (1.0f / CM);
    float var  = sq * (1.0f / CM) - mean * mean;
    float inv  = rsqrtf(var + 1e-5f);
    const float4* g4 = (const float4*)(g + part * 64);
    const float4* be4 = (const float4*)(beta + part * 64);
    #pragma unroll
    for (int c8 = 0; c8 < 8; ++c8) {
        float4 a = x[2 * c8], bq = x[2 * c8 + 1];
        float4 ga = g4[2 * c8], gb = g4[2 * c8 + 1];
        float4 ba = be4[2 * c8], bb = be4[2 * c8 + 1];
        union { ushort_t u[8]; uint4 v; } pk;
        pk.u[0] = f2bf((a.x - mean) * inv * ga.x + ba.x);
        pk.u[1] = f2bf((a.y - mean) * inv * ga.y + ba.y);
        pk.u[2] = f2bf((a.z - mean) * inv * ga.z + ba.z);
        pk.u[3] = f2bf((a.w - mean) * inv * ga.w + ba.w);
        pk.u[4] = f2bf((bq.x - mean) * inv * gb.x + bb.x);
        pk.u[5] = f2bf((bq.y - mean) * inv * gb.y + bb.y);
        pk.u[6] = f2bf((bq.z - mean) * inv * gb.z + bb.z);
        pk.u[7] = f2bf((bq.w - mean) * inv * gb.w + bb.w);
        int ck = part * 8 + c8;
        int phys = ck ^ (ml & 15);
        *(uint4*)&mnL[ml * CM + phys * 8] = pk.v;
    }

    // W fragments: direct gather from w1/w2 (column ch, stride CH floats).
    // 64 scalar L2 loads/lane, issued here so they overlap the barrier.
    int w = t >> 6, lane = t & 63, quad = lane >> 4, l15 = lane & 15;
    int ch = w * 16 + l15;
    const float* wsrc = (ch < CH) ? w1 : w2;
    int cidx = ch & 31;
    short8 bfrs[8];
    #pragma unroll
    for (int ks = 0; ks < 8; ++ks) {
        int cb = ks * 4 + quad;
        union { ushort_t u[8]; short8 v; } pw;
        #pragma unroll
        for (int e = 0; e < 8; ++e)
            pw.u[e] = f2bf(wsrc[(size_t)(cb * 8 + e) * CH + cidx]);
        bfrs[ks] = pw.v;
    }
    __syncthreads();

    f32x4 acc[4];
    #pragma unroll
    for (int a = 0; a < 4; a++) acc[a] = (f32x4)(0.f);
    #pragma unroll
    for (int ks = 0; ks < 8; ++ks) {
        int cb = ks * 4 + quad;
        #pragma unroll
        for (int mt = 0; mt < 4; ++mt) {
            int mm = mt * 16 + l15;
            short8 afr = *(const short8*)&mnL[mm * CM + ((cb ^ l15) << 3)];
            acc[mt] = __builtin_amdgcn_mfma_f32_16x16x32_bf16(afr, bfrs[ks], acc[mt], 0, 0, 0);
        }
    }

    int c = ch & 31;
    float bias = (ch < CH) ? b1[c] : b2[c];
    ushort_t* dst = (ch < CH) ? Abig : BbigT;
    #pragma unroll
    for (int mt = 0; mt < 4; ++mt) {
        int r = r0 + mt;
        union { ushort_t u[4]; uint2 v; } pk;
        #pragma unroll
        for (int reg = 0; reg < 4; ++reg) {
            int s = s0 + quad * 4 + reg;
            float mv = mask[(size_t)s * R + r];
            pk.u[reg] = f2bf((acc[mt][reg] + bias) * mv);
        }
        *(uint2*)&dst[((size_t)r * CH + c) * S + s0 + quad * 4] = pk.v;
    }
}

// ---------------------------------------------------------------------------
// K2: FUSED outer-product + projection — EXACT R0 structure (best measured:
// 54.4 us, MfmaUtil 24.5%). Two barriers per iter, single-buffered oc,
// double-buffered shB, W loaded in stage-2 loop.
// ---------------------------------------------------------------------------
__global__ __launch_bounds__(512, 4) void k_fuse(
    const ushort_t* __restrict__ Abig, const ushort_t* __restrict__ BbigT,
    const ushort_t* __restrict__ WTp, const float* __restrict__ b_out,
    const float* __restrict__ scale, float* __restrict__ out) {
    __shared__ ushort_t oc[64 * 128];        // 16 KB
    __shared__ ushort_t shB[2][32 * 128];    // 2 x 8 KB, [el*8+j][s] swizzled
    int t = threadIdx.x;
    int w = t >> 6, lane = t & 63, quad = lane >> 4, l15 = lane & 15;
    int ib = blockIdx.x >> 5, jb = blockIdx.x & 31;
    int i_g = ib * 8 + w;
    int jj = l15 & 7, elb = l15 >> 3;

    // A-frags for this wave's i-strip (register-resident, coalesced loads)
    short8 af[2][4];
    #pragma unroll
    for (int mt = 0; mt < 2; ++mt)
        #pragma unroll
        for (int ks = 0; ks < 4; ++ks)
            af[mt][ks] = *(const short8*)
                &Abig[((size_t)i_g * 32 + mt * 16 + l15) * S + ks * 32 + quad * 8];

    // B staging: thread t owns LDS row r2 = t>>4 (0..31), 16B chunk ck = t&15
    // global row = jb*256 + (r2&7)*32 + ec*4 + (r2>>3)
    int r2 = t >> 4, ck = t & 15;
    const ushort_t* gB = BbigT
        + ((size_t)jb * 256 + (r2 & 7) * 32 + (r2 >> 3)) * S + ck * 8;
    ushort_t* bdst[2];
    bdst[0] = &shB[0][r2 * 128 + ((ck ^ (r2 & 15)) << 3)];
    bdst[1] = &shB[1][r2 * 128 + ((ck ^ (r2 & 15)) << 3)];
    uint4 breg = *(const uint4*)&gB[0];      // prefetch ec=0 (e += 4 <=> +512)

    const ushort_t* Wp = WTp + (size_t)(w * 16 + l15) * 1024 + quad * 8;
    int pwr = w * 8 + jj;                    // oc pair-row this lane writes

    f32x4 acc2[4];
    #pragma unroll
    for (int pt = 0; pt < 4; ++pt) acc2[pt] = (f32x4)(0.f);

    for (int ec = 0; ec < 8; ++ec) {
        int buf = ec & 1;
        *(uint4*)bdst[buf] = breg;
        if (ec < 7) breg = *(const uint4*)&gB[(ec + 1) * 512];
        __syncthreads();   // publishes shB[buf]; closes prev stage-2 oc reads

        // ---- stage-1: OC chunk (e = ec*4 .. ec*4+3) ----
        f32x4 acc1[2][2];
        #pragma unroll
        for (int a = 0; a < 2; a++)
            #pragma unroll
            for (int b = 0; b < 2; b++) acc1[a][b] = (f32x4)(0.f);
        #pragma unroll
        for (int ks = 0; ks < 4; ++ks) {
            int chq = ks * 4 + quad;
            int r20 = elb * 8 + jj;          // nt=0: e = ec*4 + elb
            int r21 = r20 + 16;              // nt=1: e = ec*4 + 2 + elb
            short8 bf0 = *(const short8*)
                &shB[buf][r20 * 128 + ((chq ^ (r20 & 15)) << 3)];
            short8 bf1 = *(const short8*)
                &shB[buf][r21 * 128 + ((chq ^ (r21 & 15)) << 3)];
            #pragma unroll
            for (int mt = 0; mt < 2; ++mt) {
                acc1[mt][0] = __builtin_amdgcn_mfma_f32_16x16x32_bf16(
                    af[mt][ks], bf0, acc1[mt][0], 0, 0, 0);
                acc1[mt][1] = __builtin_amdgcn_mfma_f32_16x16x32_bf16(
                    af[mt][ks], bf1, acc1[mt][1], 0, 0, 0);
            }
        }
        // pack to oc: lane's 4 regs = 4 consecutive c at (pair pwr, e)
        #pragma unroll
        for (int mt = 0; mt < 2; ++mt) {
            int c00 = mt * 16 + quad * 4;
            #pragma unroll
            for (int nt = 0; nt < 2; ++nt) {
                int el = nt * 2 + elb;
                int k2l = el * 32 + c00;
                int cc = k2l >> 3;
                union { ushort_t u[4]; uint2 v; } pk;
                #pragma unroll
                for (int reg = 0; reg < 4; ++reg)
                    pk.u[reg] = f2bf(acc1[mt][nt][reg]);
                *(uint2*)((char*)oc + pwr * 256 + ((cc ^ (pwr & 7)) << 4)
                          + ((k2l & 7) << 1)) = pk.v;
            }
        }
        __syncthreads();   // publishes oc
        // ---- stage-2: out += OC_chunk x WTp_chunk (wave owns 16 z) ----
        #pragma unroll
        for (int ksl = 0; ksl < 4; ++ksl) {
            short8 wf = *(const short8*)&Wp[ec * 128 + ksl * 32];
            #pragma unroll
            for (int pt = 0; pt < 4; ++pt) {
                int pp = pt * 16 + l15;
                int cc = ksl * 4 + quad;
                short8 of = *(const short8*)
                    ((const char*)oc + pp * 256 + ((cc ^ (pp & 7)) << 4));
                acc2[pt] = __builtin_amdgcn_mfma_f32_16x16x32_bf16(
                    of, wf, acc2[pt], 0, 0, 0);
            }
        }
    }

    // ---- epilogue: bias + 1/(eps+norm) scale ----
    float bz = b_out[w * 16 + l15];
    #pragma unroll
    for (int pt = 0; pt < 4; ++pt) {
        #pragma unroll
        for (int reg = 0; reg < 4; ++reg) {
            int pp = pt * 16 + quad * 4 + reg;
            int pg = (ib * 8 + (pp >> 3)) * R + jb * 8 + (pp & 7);
            out[(size_t)pg * CZ + w * 16 + l15] = (acc2[pt][reg] + bz) * scale[pg];
        }
    }
}

// ---------------------------------------------------------------------------
extern "C" void kernel_launch(void* const* d_in, const int* in_sizes, int n_in,
                              void* d_out, int out_size, void* d_ws, size_t ws_size,
                              hipStream_t stream) {
    const float* m    = (const float*)d_in[0];
    const float* mask = (const float*)d_in[1];
    const float* g    = (const float*)d_in[2];
    const float* be   = (const float*)d_in[3];
    const float* w1   = (const float*)d_in[4];
    const float* b1   = (const float*)d_in[5];
    const float* w2   = (const float*)d_in[6];
    const float* b2   = (const float*)d_in[7];
    const float* wo   = (const float*)d_in[8];
    const float* bo   = (const float*)d_in[9];
    float* out = (float*)d_out;

    char* ws = (char*)d_ws;
    ushort_t* Abig  = (ushort_t*)ws;                        // 2 MB
    ushort_t* BbigT = Abig + (size_t)R * CH * S;            // 2 MB
    ushort_t* WTp   = BbigT + (size_t)R * CH * S;           // 256 KB
    float*    scale = (float*)(WTp + (size_t)CZ * CH * CH); // 256 KB

    k_lnproj<<<1664, 256, 0, stream>>>(m, mask, g, be, b1, b2, w1, w2, wo,
                                       Abig, BbigT, scale, WTp);
    k_fuse<<<1024, 512, 0, stream>>>(Abig, BbigT, WTp, bo, scale, out);
}